// Round 2
// 416.108 us; speedup vs baseline: 1.0344x; 1.0344x over previous
//
#include <hip/hip_runtime.h>
#include <hip/hip_bf16.h>

#define NB   64
#define NC   1024
#define NQ   128
#define DIMD 512
#define BK   64
#define NKC  (DIMD / BK)   // 8 K-chunks
#define LDK  (BK + 8)      // 72 shorts per LDS row (pad; keeps 16B align)
#define TM   128           // rows per context tile
#define NTILE (NC / TM)    // 8 tiles

using short8  = __attribute__((ext_vector_type(8))) short;
using short4v = __attribute__((ext_vector_type(4))) short;
using f32x4   = __attribute__((ext_vector_type(4))) float;
typedef __fp16 half2v __attribute__((ext_vector_type(2)));

__device__ inline float dot4(float4 a, float4 b) {
    return a.x * b.x + a.y * b.y + a.z * b.z + a.w * b.w;
}

// ---------------------------------------------------------------------------
// K1: bf16 MFMA GEMM -> sim; epilogue converts to E = exp(sim), spills E as
// fp16 (col-major per tile) and writes per-tile column sums of the ROUNDED E
// (so K2's normalization is exactly consistent with the spilled values).
// Grid (NB, NTILE), 256 threads = 4 waves in a 2x2 grid over the 128x128 tile.
// ---------------------------------------------------------------------------
__global__ __launch_bounds__(256) void gemm_stats(
    const float* __restrict__ ctx, const float* __restrict__ qry,
    const float* __restrict__ w0, float* __restrict__ stats,
    unsigned short* __restrict__ eh)
{
    __shared__ __attribute__((aligned(16))) short As[TM][LDK];  // bf16(c * wm)
    __shared__ __attribute__((aligned(16))) short Bs[NQ][LDK];  // bf16(q)
    __shared__ __attribute__((aligned(16))) float w0L[3 * DIMD];
    __shared__ float cwL[TM], qwL[NQ];
    __shared__ float sL[2][NQ];

    const int tid  = threadIdx.x;
    const int b    = blockIdx.x;
    const int bt   = blockIdx.y;
    const int i0   = bt * TM;
    const int w    = tid >> 6;
    const int lane = tid & 63;
    const int wr   = w >> 1, wcg = w & 1;
    const int RB   = wr * 64, CB = wcg * 64;
    const int n16  = lane & 15, qd = lane >> 4;

    for (int idx = tid; idx < 3 * DIMD; idx += 256) w0L[idx] = w0[idx];

    f32x4 acc[4][4];
#pragma unroll
    for (int ri = 0; ri < 4; ri++)
#pragma unroll
        for (int ci = 0; ci < 4; ci++)
#pragma unroll
            for (int e = 0; e < 4; e++) acc[ri][ci][e] = 0.f;

    // staging: 16 lanes per row (fully coalesced 256B segments), 4 rows/inst,
    // 8 row-steps (u) cover the wave's 32 rows.
    const int col4  = n16 * 4;
    const int srow0 = w * 32 + qd;                 // row for u=0; +4 per u
    const float* cBase = ctx + ((size_t)(b * NC + i0 + srow0)) * DIMD + col4;
    const float* qBase = qry + ((size_t)(b * NQ + srow0)) * DIMD + col4;
    float cwp[8], qwp[8];
#pragma unroll
    for (int u = 0; u < 8; u++) { cwp[u] = 0.f; qwp[u] = 0.f; }

    for (int kc = 0; kc < NKC; kc++) {
        const int k0 = kc * BK;
        __syncthreads();   // prior MFMA done reading As/Bs (covers w0L on kc=0)
        float4 wcv = *(const float4*)&w0L[k0 + col4];
        float4 wqv = *(const float4*)&w0L[DIMD + k0 + col4];
        float4 wmv = *(const float4*)&w0L[2 * DIMD + k0 + col4];
#pragma unroll
        for (int u = 0; u < 8; u++) {
            const int row = w * 32 + u * 4 + qd;
            float4 v = *(const float4*)(cBase + k0 + (size_t)u * 4 * DIMD);
            cwp[u] += dot4(v, wcv);
            union { __hip_bfloat162 h[2]; short4v s; } pc;
            pc.h[0] = __float22bfloat162_rn(make_float2(v.x * wmv.x, v.y * wmv.y));
            pc.h[1] = __float22bfloat162_rn(make_float2(v.z * wmv.z, v.w * wmv.w));
            *(short4v*)&As[row][col4] = pc.s;

            float4 q = *(const float4*)(qBase + k0 + (size_t)u * 4 * DIMD);
            qwp[u] += dot4(q, wqv);
            union { __hip_bfloat162 h[2]; short4v s; } pq;
            pq.h[0] = __float22bfloat162_rn(make_float2(q.x, q.y));
            pq.h[1] = __float22bfloat162_rn(make_float2(q.z, q.w));
            *(short4v*)&Bs[row][col4] = pq.s;
        }
        __syncthreads();
        // MFMA: A[m=lane&15][k=qd*8+j], B[n=lane&15][k=qd*8+j]
#pragma unroll
        for (int ks = 0; ks < BK / 32; ks++) {
            const int kb = ks * 32 + qd * 8;
            short8 af[4], bfr[4];
#pragma unroll
            for (int ri = 0; ri < 4; ri++) af[ri] = *(const short8*)&As[RB + ri * 16 + n16][kb];
#pragma unroll
            for (int ci = 0; ci < 4; ci++) bfr[ci] = *(const short8*)&Bs[CB + ci * 16 + n16][kb];
#pragma unroll
            for (int ri = 0; ri < 4; ri++)
#pragma unroll
                for (int ci = 0; ci < 4; ci++)
                    acc[ri][ci] = __builtin_amdgcn_mfma_f32_16x16x32_bf16(
                        af[ri], bfr[ci], acc[ri][ci], 0, 0, 0);
        }
    }

    // reduce cw/qw partials: each u-slot's value lives on 16 lanes (same row)
#pragma unroll
    for (int u = 0; u < 8; u++) {
        float c = cwp[u], q = qwp[u];
#pragma unroll
        for (int off = 1; off < 16; off <<= 1) {
            c += __shfl_xor(c, off);
            q += __shfl_xor(q, off);
        }
        if (n16 == 0) {
            const int row = w * 32 + u * 4 + qd;
            cwL[row] = c; qwL[row] = q;
        }
    }
    __syncthreads();

    // Epilogue: v = acc + cw_i + qw_j; E = exp(v); spill fp16 E (col-major);
    // Z accumulated from the ROUNDED fp16 values for exact consistency.
    // C/D layout (16x16x32): col = lane&15, row = (lane>>4)*4 + reg
#pragma unroll
    for (int ci = 0; ci < 4; ci++) {
        const int col = CB + ci * 16 + n16;
        const float qwv = qwL[col];
        unsigned short* eCol = eh + ((size_t)(b * NTILE + bt) * NQ + col) * TM;
        float s = 0.f;
#pragma unroll
        for (int ri = 0; ri < 4; ri++) {
            const int rbase = RB + ri * 16 + qd * 4;
            float e0 = __expf(acc[ri][ci][0] + cwL[rbase + 0] + qwv);
            float e1 = __expf(acc[ri][ci][1] + cwL[rbase + 1] + qwv);
            float e2 = __expf(acc[ri][ci][2] + cwL[rbase + 2] + qwv);
            float e3 = __expf(acc[ri][ci][3] + cwL[rbase + 3] + qwv);
            half2v h01 = __builtin_amdgcn_cvt_pkrtz(e0, e1);
            half2v h23 = __builtin_amdgcn_cvt_pkrtz(e2, e3);
            s += (float)h01[0] + (float)h01[1] + (float)h23[0] + (float)h23[1];
            uint2 pk;
            pk.x = __builtin_bit_cast(unsigned, h01);
            pk.y = __builtin_bit_cast(unsigned, h23);
            *(uint2*)&eCol[rbase] = pk;
        }
        s += __shfl_xor(s, 16);
        s += __shfl_xor(s, 32);
        if (qd == 0) sL[wr][col] = s;
    }
    __syncthreads();
    if (tid < NQ)
        stats[(size_t)(b * NTILE + bt) * NQ + tid] = sL[0][tid] + sL[1][tid];
}

// ---------------------------------------------------------------------------
// K2: per (b, tile): iz[j] = 1/sum_tiles Z (folded combine_stats);
// r_i = sum_j E_ij * iz_j  (fp16 E, NO expf);  bpart[d] = sum_i r_i c_i[d];
// plus this tile's 64-column slice of arow[b][d] = sum_j q_j[d] (folded arow).
// Grid (NB, NTILE), block 256.
// ---------------------------------------------------------------------------
__global__ __launch_bounds__(256) void rb2(
    const float* __restrict__ ctx, const float* __restrict__ qry,
    const unsigned short* __restrict__ eh, const float* __restrict__ stats,
    float* __restrict__ bpart, float* __restrict__ arow)
{
    __shared__ __attribute__((aligned(16))) unsigned short eL[NQ * TM];
    __shared__ float izL[NQ];
    __shared__ float rpart[2][TM];
    __shared__ float rfin[TM];
    __shared__ float qL[4][64];

    const int tid = threadIdx.x;
    const int b = blockIdx.x, bt = blockIdx.y;
    const int i0 = bt * TM;

    if (tid < NQ) {
        float ssum = 0.f;
#pragma unroll
        for (int t8 = 0; t8 < NTILE; t8++)
            ssum += stats[(size_t)(b * NTILE + t8) * NQ + tid];
        izL[tid] = 1.0f / ssum;
    }
    const unsigned short* tileSrc = eh + (size_t)(b * NTILE + bt) * NQ * TM;
#pragma unroll
    for (int it = 0; it < 8; it++) {
        const int idx = (tid + it * 256) * 8;   // 8 ushorts = 16B per thread
        *(uint4*)&eL[idx] = *(const uint4*)&tileSrc[idx];
    }
    __syncthreads();

    const int i = tid & 127, jh = tid >> 7;
    float r = 0.f;
    for (int j2 = 0; j2 < 64; j2++) {
        const int j = jh * 64 + j2;
        __fp16 hv = __builtin_bit_cast(__fp16, eL[j * TM + i]);
        r += (float)hv * izL[j];
    }
    rpart[jh][i] = r;
    __syncthreads();
    if (tid < TM) rfin[tid] = rpart[0][tid] + rpart[1][tid];
    __syncthreads();

    // bpart[d] = sum_i r_i c_i[d] over this tile's 128 ctx rows (L3-warm)
    const int d0 = tid * 2;
    float bx = 0.f, by = 0.f;
    const float* cb2 = ctx + ((size_t)b * NC + i0) * DIMD + d0;
    for (int ii = 0; ii < TM; ii++) {
        float  rv = rfin[ii];
        float2 cv = *(const float2*)(cb2 + (size_t)ii * DIMD);
        bx += rv * cv.x; by += rv * cv.y;
    }
    float* bp = bpart + (size_t)(b * NTILE + bt) * DIMD + d0;
    bp[0] = bx; bp[1] = by;

    // arow slice: this block computes arow[b][bt*64 .. bt*64+64)
    const int dcol = tid & 63, rgrp = tid >> 6;
    float qs = 0.f;
    const float* qb = qry + (size_t)b * NQ * DIMD + bt * 64 + dcol;
    for (int t = 0; t < 32; t++)
        qs += qb[(size_t)(t * 4 + rgrp) * DIMD];
    qL[rgrp][dcol] = qs;
    __syncthreads();
    if (tid < 64)
        arow[(size_t)b * DIMD + bt * 64 + tid] =
            qL[0][tid] + qL[1][tid] + qL[2][tid] + qL[3][tid];
}

// ---------------------------------------------------------------------------
// K3: reduce Brow partials + broadcast-write A and B (nontemporal: output is
// write-once, keep it out of L2). Grid (NB, 32), block 256.
// ---------------------------------------------------------------------------
__global__ void broadcast_out(const float* __restrict__ arow, const float* __restrict__ bpart,
                              float* __restrict__ out)
{
    const int b = blockIdx.x, ic = blockIdx.y;
    const int t = threadIdx.x;
    const int half = t >> 7;          // 0 -> A, 1 -> B (wave-uniform)
    const int l = t & 127;
    const int d0 = l * 4;
    f32x4 val;
    if (half == 0) {
        val = *(const f32x4*)&arow[(size_t)b * DIMD + d0];
    } else {
        val[0] = val[1] = val[2] = val[3] = 0.f;
        for (int t8 = 0; t8 < NTILE; t8++) {
            f32x4 v = *(const f32x4*)&bpart[(size_t)(b * NTILE + t8) * DIMD + d0];
            val[0] += v[0]; val[1] += v[1]; val[2] += v[2]; val[3] += v[3];
        }
    }
    size_t base = (size_t)half * ((size_t)NB * NC * DIMD)
                + ((size_t)b * NC + (size_t)ic * 32) * DIMD + d0;
    for (int i = 0; i < 32; i++)
        __builtin_nontemporal_store(val, (f32x4*)&out[base + (size_t)i * DIMD]);
}

extern "C" void kernel_launch(void* const* d_in, const int* in_sizes, int n_in,
                              void* d_out, int out_size, void* d_ws, size_t ws_size,
                              hipStream_t stream)
{
    const float* ctx = (const float*)d_in[0];  // (64,1024,512) f32
    const float* qry = (const float*)d_in[1];  // (64,128,512) f32
    const float* w0  = (const float*)d_in[2];  // (1536,) f32
    float* out = (float*)d_out;
    float* ws  = (float*)d_ws;

    float* stats = ws;                          // 64*8*128 = 65536 floats
    float* arow  = ws + 65536;                  // 64*512   = 32768
    float* bpart = ws + 98304;                  // 64*8*512 = 262144
    unsigned short* eh = (unsigned short*)(ws + 360448);  // 64*8*128*128 fp16 = 16.8 MB

    gemm_stats<<<dim3(NB, NTILE), 256, 0, stream>>>(ctx, qry, w0, stats, eh);
    rb2<<<dim3(NB, NTILE), 256, 0, stream>>>(ctx, qry, eh, stats, bpart, arow);
    broadcast_out<<<dim3(NB, 32), 256, 0, stream>>>(arow, bpart, out);
}